// Round 12
// baseline (236.301 us; speedup 1.0000x reference)
//
#include <hip/hip_runtime.h>
#include <stdint.h>

// Problem constants
#define BB 2
#define SS 2048
#define HIDD 2048
#define HH 16
#define KVH 4
#define DD 128
#define KDIM 2048

typedef short bf16x4 __attribute__((ext_vector_type(4)));
typedef short bf16x8 __attribute__((ext_vector_type(8)));
typedef float f32x4 __attribute__((ext_vector_type(4)));
typedef float f32x16 __attribute__((ext_vector_type(16)));

__device__ __forceinline__ unsigned short f2b(float f) {
  union { float f; unsigned u; } v; v.f = f;
  unsigned r = v.u + 0x7FFFu + ((v.u >> 16) & 1u);
  return (unsigned short)(r >> 16);
}

__device__ __forceinline__ float b2f(unsigned short u) {
  union { unsigned u; float f; } v; v.u = ((unsigned)u) << 16;
  return v.f;
}

__device__ __forceinline__ unsigned cvtpk_bf16(float a, float b) {
  unsigned r;
  asm("v_cvt_pk_bf16_f32 %0, %1, %2" : "=v"(r) : "v"(a), "v"(b));
  return r;
}

// async global->LDS, 16B per lane; LDS dest is wave-uniform base + lane*16
__device__ __forceinline__ void gload16(const unsigned short* g, unsigned short* l) {
  __builtin_amdgcn_global_load_lds(
      (const __attribute__((address_space(1))) unsigned int*)(g),
      (__attribute__((address_space(3))) unsigned int*)(l), 16, 0, 0);
}

// 16B LDS tile read
__device__ __forceinline__ bf16x8 ldT(const char* lds, int byteoff) {
  union { bf16x8 v; int4 q; } u;
  u.q = *reinterpret_cast<const int4*>(lds + byteoff);
  return u.v;
}

template <int N>
__device__ __forceinline__ void waitv() {
  if constexpr (N == 0) asm volatile("s_waitcnt vmcnt(0)" ::: "memory");
  else if constexpr (N == 1) asm volatile("s_waitcnt vmcnt(1)" ::: "memory");
  else if constexpr (N == 2) asm volatile("s_waitcnt vmcnt(2)" ::: "memory");
  else if constexpr (N == 3) asm volatile("s_waitcnt vmcnt(3)" ::: "memory");
  else if constexpr (N == 4) asm volatile("s_waitcnt vmcnt(4)" ::: "memory");
  else asm volatile("s_waitcnt vmcnt(6)" ::: "memory");
}

__global__ __launch_bounds__(256) void k_convert(const float* __restrict__ in,
                                                 unsigned short* __restrict__ out, int n4) {
  int i = blockIdx.x * 256 + threadIdx.x;
  int stride = gridDim.x * 256;
  for (; i < n4; i += stride) {
    float4 v = reinterpret_cast<const float4*>(in)[i];
    ushort4 o;
    o.x = f2b(v.x); o.y = f2b(v.y); o.z = f2b(v.z); o.w = f2b(v.w);
    int ci = i & 511;
    int t = ci & 7;
    int ci2 = (ci & ~7) | ((t & 3) << 1) | (t >> 2);
    reinterpret_cast<ushort4*>(out)[(i & ~511) | ci2] = o;
  }
}

// in: (K,N) fp32 row-major -> out: (N,K) bf16 row-major with K-dim interleave perm
__global__ __launch_bounds__(256) void k_transpose(const float* __restrict__ in,
                                                   unsigned short* __restrict__ out,
                                                   int K, int N) {
  __shared__ float tile[32][33];
  int n0 = blockIdx.x * 32, k0 = blockIdx.y * 32;
  int tx = threadIdx.x, ty = threadIdx.y;
#pragma unroll
  for (int j = 0; j < 32; j += 8)
    tile[ty + j][tx] = in[(size_t)(k0 + ty + j) * N + n0 + tx];
  __syncthreads();
  int kp = ((tx >> 2) & 3) * 8 + (tx & 3) + ((tx >> 4) << 2);
#pragma unroll
  for (int j = 0; j < 32; j += 8)
    out[(size_t)(n0 + ty + j) * K + k0 + kp] = f2b(tile[tx][ty + j]);
}

// ===== BM x 256 GEMM, m201-literal 8-phase schedule =====
// 512 thr = 8 waves (2M x 4N), wave tile (BM/2) x 64, BK=64.
// Phase = {ds_read quadrant; stage half-tile; vmcnt(N); barrier; lgkmcnt(0);
//          setprio(1); MFMA; setprio(0); barrier}  — two barriers per phase.
// vmcnt counts by in-order retirement: LA=BM/128 loads per A-half, LB=2 per B-half.
template <int EPI, int BM>
__global__ __launch_bounds__(512) void k_gemm8(
    const unsigned short* __restrict__ A, const unsigned short* __restrict__ Bt,
    float* __restrict__ outF, unsigned short* __restrict__ qws,
    unsigned short* __restrict__ kws, unsigned short* __restrict__ vTws,
    float* __restrict__ koutF, float* __restrict__ voutF,
    const float* __restrict__ cosT, const float* __restrict__ sinT) {
  constexpr int LA = BM / 128;      // gload instrs per A-half per wave
  constexpr int LB = 2;             // per B-half per wave
  constexpr int ASTR = BM * 64;     // elems per A buffer
  constexpr int BSTR = 256 * 64;
  constexpr int MF = BM / 64;       // m-frags per half
  constexpr int LSH = (BM == 256) ? 6 : 5;
  extern __shared__ __align__(16) unsigned short smem[];
  unsigned short* lAb = smem;              // [2][ASTR]
  unsigned short* lBb = smem + 2 * ASTR;   // [2][BSTR]

  const int bid = blockIdx.y * gridDim.x + blockIdx.x;
  const int nwg = gridDim.x * gridDim.y;   // %8 == 0
  const int mt = gridDim.x;
  const int swz = (bid & 7) * (nwg >> 3) + (bid >> 3);
  const int rowbase = (swz % mt) * BM;
  const int colbase = (swz / mt) * 256;

  const int tid = threadIdx.x;
  const int wv = tid >> 6, lane = tid & 63;
  const int wr = wv >> 2, wc = wv & 3;
  const int g = lane >> 4, c = lane & 15;

  const int srow8 = lane >> 3;
  const int gch = (lane & 7) ^ srow8;   // source chunk (XOR swizzle baked in)
  const unsigned short* aS[LA][2];
  const unsigned short* bS[2][2];
  int aOff[LA][2], bOff[2][2];
#pragma unroll
  for (int j = 0; j < LA; ++j)
#pragma unroll
    for (int h = 0; h < 2; ++h) {
      int s = wv * LA + j;
      int q = s * 8 + srow8;
      int rA = (q >> LSH) * (BM / 2) + h * (BM / 4) + (q & (BM / 4 - 1));
      aS[j][h] = A + (size_t)(rowbase + rA) * KDIM + gch * 8;
      aOff[j][h] = (h * (BM / 2) + s * 8) * 64;
    }
#pragma unroll
  for (int j = 0; j < 2; ++j)
#pragma unroll
    for (int h = 0; h < 2; ++h) {
      int s = wv * 2 + j;
      int q = s * 8 + srow8;
      int rB = (q >> 5) * 64 + h * 32 + (q & 31);
      bS[j][h] = Bt + (size_t)(colbase + rB) * KDIM + gch * 8;
      bOff[j][h] = (h * 128 + s * 8) * 64;
    }

  f32x4 acc[2 * MF][4] = {};
  bf16x8 af[MF][2], bfr[4][2];
  const int NT = KDIM / 64;  // 32

#define STAGE_A(buf, kt, h)                                               \
  _Pragma("unroll") for (int j = 0; j < LA; ++j)                          \
      gload16(aS[j][h] + (kt) * 64, lAb + (buf) * ASTR + aOff[j][h]);
#define STAGE_B(buf, kt, h)                                               \
  _Pragma("unroll") for (int j = 0; j < 2; ++j)                           \
      gload16(bS[j][h] + (kt) * 64, lBb + (buf) * BSTR + bOff[j][h]);
#define LDA(buf, mh)                                                      \
  _Pragma("unroll") for (int mm = 0; mm < MF; ++mm) {                     \
    int sr = (mh) * (BM / 2) + wr * (BM / 4) + mm * 16 + c;               \
    _Pragma("unroll") for (int kk = 0; kk < 2; ++kk) {                    \
      int slot = (kk * 4 + g) ^ (c & 7);                                  \
      af[mm][kk] = *reinterpret_cast<const bf16x8*>(                      \
          lAb + (buf) * ASTR + sr * 64 + slot * 8);                       \
    } }
#define LDB(buf, nh)                                                      \
  _Pragma("unroll") for (int nn = 0; nn < 2; ++nn) {                      \
    int sr = (nh) * 128 + wc * 32 + nn * 16 + c;                          \
    _Pragma("unroll") for (int kk = 0; kk < 2; ++kk) {                    \
      int slot = (kk * 4 + g) ^ (c & 7);                                  \
      bfr[(nh) * 2 + nn][kk] = *reinterpret_cast<const bf16x8*>(          \
          lBb + (buf) * BSTR + sr * 64 + slot * 8);                       \
    } }
#define MM(mh, nh)                                                        \
  _Pragma("unroll") for (int mm = 0; mm < MF; ++mm)                       \
  _Pragma("unroll") for (int nn = 0; nn < 2; ++nn)                        \
  _Pragma("unroll") for (int kk = 0; kk < 2; ++kk)                        \
    acc[(mh) * MF + mm][(nh) * 2 + nn] =                                  \
        __builtin_amdgcn_mfma_f32_16x16x32_bf16(                          \
            af[mm][kk], bfr[(nh) * 2 + nn][kk],                           \
            acc[(mh) * MF + mm][(nh) * 2 + nn], 0, 0, 0);
#define SCHB __builtin_amdgcn_sched_barrier(0);
#define SB __builtin_amdgcn_s_barrier();
#define LGKM asm volatile("s_waitcnt lgkmcnt(0)" ::: "memory");
#define MFMAWIN(mh, nh)                                                   \
  LGKM SCHB __builtin_amdgcn_s_setprio(1);                                \
  MM(mh, nh) __builtin_amdgcn_s_setprio(0); SCHB SB

  // prologue: tile 0's 4 half-tiles; certify A0,B0
  STAGE_A(0, 0, 0) STAGE_B(0, 0, 0) STAGE_B(0, 0, 1) STAGE_A(0, 0, 1)
  waitv<LA + LB>(); SCHB SB

  for (int kt = 0; kt < NT - 1; ++kt) {
    const int buf = kt & 1, nbuf = buf ^ 1;
    // phase 0
    LDA(buf, 0) LDB(buf, 0)
    STAGE_A(nbuf, kt + 1, 0)
    waitv<2 * LA>(); SCHB SB      // certify B1(kt)
    MFMAWIN(0, 0)
    // phase 1
    LDB(buf, 1)
    STAGE_B(nbuf, kt + 1, 0)
    waitv<LA + LB>(); SCHB SB     // certify A1(kt)
    MFMAWIN(0, 1)
    // phase 2
    LDA(buf, 1)
    STAGE_B(nbuf, kt + 1, 1)
    SCHB SB                       // no vmcnt needed
    MFMAWIN(1, 0)
    // phase 3
    STAGE_A(nbuf, kt + 1, 1)
    waitv<LA + LB>(); SCHB SB     // certify A0,B0(kt+1)
    MFMAWIN(1, 1)
  }
  {  // last tile: counted drain LA -> 0
    const int buf = (NT - 1) & 1;
    LDA(buf, 0) LDB(buf, 0)
    waitv<LA>(); SCHB SB
    MFMAWIN(0, 0)
    LDB(buf, 1)
    waitv<0>(); SCHB SB
    MFMAWIN(0, 1)
    LDA(buf, 1)
    SCHB SB
    MFMAWIN(1, 0)
    __builtin_amdgcn_s_setprio(1);
    MM(1, 1)
    __builtin_amdgcn_s_setprio(0);
  }

  if (EPI == 0) {
#pragma unroll
    for (int m = 0; m < 2 * MF; ++m)
#pragma unroll
      for (int n = 0; n < 4; ++n)
#pragma unroll
        for (int i = 0; i < 4; ++i) {
          int R = rowbase + wr * (BM / 2) + m * 16 + g * 4 + i;
          int Cc = colbase + wc * 64 + n * 16 + c;
          outF[(size_t)R * 2048 + Cc] = acc[m][n][i];
        }
  } else {
#pragma unroll
    for (int m = 0; m < 2 * MF; ++m) {
#pragma unroll
      for (int n = 0; n < 4; ++n) {
#pragma unroll
        for (int i = 0; i < 4; ++i) {
          float val = acc[m][n][i];
          float partner = __shfl_xor(val, 1, 64);
          int R = rowbase + wr * (BM / 2) + m * 16 + g * 4 + i;
          int Cc = colbase + wc * 64 + n * 16 + c;
          int b = R >> 11, s = R & 2047;
          int d = Cc & 127;
          int j = d >> 1;
          float cs = cosT[s * 64 + j], sn = sinT[s * 64 + j];
          float ro = ((d & 1) == 0) ? (val * cs - partner * sn)
                                    : (partner * sn + val * cs);
          if (Cc < 2048) {
            int h = Cc >> 7;
            qws[((size_t)(b * HH + h) * SS + s) * DD + d] = f2b(ro);
          } else if (Cc < 2560) {
            int kvh = (Cc - 2048) >> 7;
            size_t idx = ((size_t)(b * KVH + kvh) * SS + s) * DD + d;
            koutF[idx] = ro;
            int d16 = d & 15;
            int dp = (d & ~15) | (d16 & 3) | ((d16 & 4) << 1) | ((d16 & 8) >> 1);
            kws[((size_t)(b * KVH + kvh) * SS + s) * DD + dp] = f2b(ro);
          } else {
            int kvh = (Cc - 2560) >> 7;
            size_t idx = ((size_t)(b * KVH + kvh) * SS + s) * DD + d;
            voutF[idx] = val;
            int s16 = s & 15;
            int sp = (s & ~15) | (s16 & 3) | ((s16 & 4) << 1) | ((s16 & 8) >> 1);
            vTws[((size_t)(b * KVH + kvh) * DD + d) * SS + sp] = f2b(val);
          }
        }
      }
    }
  }
#undef STAGE_A
#undef STAGE_B
#undef LDA
#undef LDB
#undef MM
#undef SCHB
#undef SB
#undef LGKM
#undef MFMAWIN
}

// LPT job table: 24 jobs/head sorted by tile count desc.
__constant__ int JC[24] = {7,15,15,14,14,6,13,13,12,12,5,11,11,10,10,4,9,9,8,8,3,2,1,0};
__constant__ int JP[24] = {0,0,1, 0,1, 0,0,1, 0,1, 0,0,1, 0,1, 0,0,1, 0,1, 0,0,0,0};

// Flash attention, 32x32 MFMA, double-swapped operands (unchanged from R7-R10).
__global__ __launch_bounds__(256, 2) void k_attn(const unsigned short* __restrict__ qws,
                                                 const unsigned short* __restrict__ kws,
                                                 const unsigned short* __restrict__ vT,
                                                 unsigned short* __restrict__ aows,
                                                 unsigned short* __restrict__ pO,
                                                 float* __restrict__ pml) {
  __shared__ __align__(16) char lds[2][32768];  // per buf: K 16KB | V 16KB
  const int tid = threadIdx.x;
  const int lane = tid & 63;
  const int w = tid >> 6;
  const int lq = lane & 31;
  const int hi = lane >> 5;

  const int bid = blockIdx.x;
  const int j = bid >> 5;
  const int y = bid & 31;
  const int head = 4 * (y & 7) + ((y >> 3) & 3);
  const int c = JC[j];
  const int part = JP[j];
  const bool split = (c >= 8);
  const int tstart = split ? (part ? (c + 1) : 0) : 0;
  const int tend = split ? (part ? (2 * c + 2) : (c + 1)) : (2 * c + 2);

  const int b = head >> 4, h = head & 15;
  const int kv = h >> 2;
  const int q0w = c * 128 + w * 32;
  const int qg = q0w + lq;
  const float cl2 = 0.12751743f;

  const unsigned short* qp = qws + ((size_t)(b * HH + h) * SS + qg) * DD;
  bf16x8 qf[8];
#pragma unroll
  for (int ks = 0; ks < 8; ++ks) {
    union { bf16x8 v8; bf16x4 v4[2]; } u;
    const unsigned short* p = qp + ks * 16 + hi * 4;
    u.v4[0] = *reinterpret_cast<const bf16x4*>(p);
    u.v4[1] = *reinterpret_cast<const bf16x4*>(p + 8);
    qf[ks] = u.v8;
  }

  const unsigned short* kbase = kws + (size_t)(b * KVH + kv) * SS * DD;
  const unsigned short* vbase = vT + (size_t)(b * KVH + kv) * DD * SS;

  const unsigned short* kSrc[4];
  const unsigned short* vSrc[4];
  int ldsOff[4];
#pragma unroll
  for (int j2 = 0; j2 < 4; ++j2) {
    int i = w + 4 * j2;
    int ks = i >> 1, half = i & 1;
    kSrc[j2] = kbase + (size_t)(half * 32 + (lane >> 1)) * DD + ks * 16 + (lane & 1) * 8;
    int kkv = i >> 2, d0v = i & 3;
    vSrc[j2] = vbase + (size_t)(d0v * 32 + (lane >> 1)) * SS + kkv * 16 + (lane & 1) * 8;
    ldsOff[j2] = i * 1024;
  }

  auto STAGE = [&](int t, int buf) {
    char* lK = lds[buf];
    char* lV = lds[buf] + 16384;
#pragma unroll
    for (int j2 = 0; j2 < 4; ++j2) {
      gload16(kSrc[j2] + (size_t)t * 64 * DD, (unsigned short*)(lK + ldsOff[j2]));
      gload16(vSrc[j2] + (size_t)t * 64, (unsigned short*)(lV + ldsOff[j2]));
    }
  };

  f32x16 o[4] = {};
  float mrow = -1e30f, lrow = 0.f;

  STAGE(tstart, 0);
  STAGE(tstart + 1, 1);
  asm volatile("s_waitcnt vmcnt(8)" ::: "memory");
  __builtin_amdgcn_sched_barrier(0);
  __builtin_amdgcn_s_barrier();

  for (int t = tstart; t < tend; ++t) {
    const int cur = (t - tstart) & 1;

    if (t * 64 <= q0w + 31) {
      const char* lK = lds[cur];
      const char* lV = lds[cur] + 16384;
      const bool full2 = (t * 64 + 32 <= q0w + 31);

      f32x16 s0 = {}, s1 = {};
      __builtin_amdgcn_s_setprio(1);
#pragma unroll
      for (int ks = 0; ks < 8; ++ks) {
        int off = ks * 2048 + lq * 32 + hi * 16;
        s0 = __builtin_amdgcn_mfma_f32_32x32x16_bf16(ldT(lK, off), qf[ks], s0, 0, 0, 0);
      }
      if (full2) {
#pragma unroll
        for (int ks = 0; ks < 8; ++ks) {
          int off = ks * 2048 + 1024 + lq * 32 + hi * 16;
          s1 = __builtin_amdgcn_mfma_f32_32x32x16_bf16(ldT(lK, off), qf[ks], s1, 0, 0, 0);
        }
      }
      __builtin_amdgcn_s_setprio(0);

      const int kq = t * 64 + 4 * hi - qg;
      float p[32];
      float rowmax = -1e30f;
      const bool m0 = (t * 64 + 31) > q0w;
#pragma unroll
      for (int r = 0; r < 16; ++r) {
        float v = s0[r] * cl2;
        if (m0) {
          int kl = (r & 3) + 8 * (r >> 2);
          if (kq + kl > 0) v = -1e30f;
        }
        p[r] = v;
        rowmax = fmaxf(rowmax, v);
      }
      if (full2) {
        const bool m1 = (t * 64 + 63) > q0w;
#pragma unroll
        for (int r = 0; r < 16; ++r) {
          float v = s1[r] * cl2;
          if (m1) {
            int kl = 32 + (r & 3) + 8 * (r >> 2);
            if (kq + kl > 0) v = -1e30f;
          }
          p[16 + r] = v;
          rowmax = fmaxf(rowmax, v);
        }
      }
      rowmax = fmaxf(rowmax, __shfl_xor(rowmax, 32, 64));

      if (__any(rowmax > mrow + 8.f)) {
        float mnew = fmaxf(mrow, rowmax);
        float fac = exp2f(mrow - mnew);
        mrow = mnew;
        lrow *= fac;
#pragma unroll
        for (int d0 = 0; d0 < 4; ++d0)
#pragma unroll
          for (int r = 0; r < 16; ++r) o[d0][r] *= fac;
      }

      float rsum = 0.f;
#pragma unroll
      for (int e = 0; e < 16; ++e) { p[e] = exp2f(p[e] - mrow); rsum += p[e]; }
      if (full2) {
#pragma unroll
        for (int e = 16; e < 32; ++e) { p[e] = exp2f(p[e] - mrow); rsum += p[e]; }
      }
      rsum += __shfl_xor(rsum, 32, 64);
      lrow += rsum;

      bf16x8 pf[4];
#pragma unroll
      for (int s4 = 0; s4 < 2; ++s4) {
        union { bf16x8 v; unsigned u[4]; } pu;
        int base = s4 * 8;
#pragma unroll
        for (int jj = 0; jj < 4; ++jj)
          pu.u[jj] = cvtpk_bf16(p[base + 2 * jj], p[base + 2 * jj + 1]);
        pf[s4] = pu.v;
      }
      if (full2) {
#pragma unroll
        for (int s4 = 2; s4 < 4; ++s4) {
          union { bf16x8 v; unsigned u[4]; } pu;
          int base = 16 + (s4 - 2) * 8;
#pragma unroll
          for (int jj = 0; jj < 4; ++jj)
            pu.u[jj] = cvtpk_bf16(p[base + 2 * jj], p[base + 2 * jj + 1]);
          pf[s4] = pu.v;
        }
      }

      __builtin_amdgcn_s_setprio(1);
#pragma unroll
      for (int d0 = 0; d0 < 4; ++d0)
#pragma unroll
        for (int kk = 0; kk < 2; ++kk) {
          int off = (kk * 4 + d0) * 1024 + lq * 32 + hi * 16;
          o[d0] = __builtin_amdgcn_mfma_f32_32x32x16_bf16(ldT(lV, off), pf[kk], o[d0], 0, 0, 0);
        }
      if (full2) {
#pragma unroll
        for (int d0 = 0; d0 < 4; ++d0)
#pragma unroll
          for (int kk = 2; kk < 4; ++kk) {
            int off = (kk * 4 + d0) * 1024 + lq * 32 + hi * 16;
            o[d0] = __builtin_amdgcn_mfma_f32_32x32x16_bf16(ldT(lV, off), pf[kk], o[d0], 0, 0, 0);
          }
      }
      __builtin_amdgcn_s_setprio(0);
    }

    if (t + 1 < tend) {
      __builtin_amdgcn_s_barrier();
      if (t + 2 < tend) {
        STAGE(t + 2, cur);
        asm volatile("s_waitcnt vmcnt(8)" ::: "memory");
      } else {
        asm volatile("s_waitcnt vmcnt(0)" ::: "memory");
      }
      __builtin_amdgcn_sched_barrier(0);
      __builtin_amdgcn_s_barrier();
    }
  }

  if (!split) {
    float linv = 1.f / lrow;
    unsigned short* op = aows + ((size_t)(b * SS + qg)) * 2048 + h * 128;
#pragma unroll
    for (int d0 = 0; d0 < 4; ++d0)
#pragma unroll
      for (int rq = 0; rq < 4; ++rq) {
        unsigned w0 = cvtpk_bf16(o[d0][rq * 4 + 0] * linv, o[d0][rq * 4 + 1] * linv);
        unsigned w1 = cvtpk_bf16(o[d0][rq * 4 + 2] * linv, o[d0][rq * 4 + 3] * linv);
        int2 st2; st2.x = (int)w0; st2.y = (int)w1;
        int pos = 8 * ((2 * rq + hi) & 3) + 4 * (rq >> 1);
        *reinterpret_cast<int2*>(op + d0 * 32 + pos) = st2;
      }
  } else {
    int c8 = c - 8;
    int row = qg - c * 128;
    unsigned short* op = pO + ((((size_t)(head * 8 + c8) * 2 + part) * 128) + row) * 128;
#pragma unroll
    for (int d0 = 0; d0 < 4; ++d0)
#pragma unroll
      for (int rq = 0; rq < 4; ++rq) {
        unsigned w0 = cvtpk_bf16(o[d0][rq * 4 + 0], o[d0][rq * 4 + 1]);
        unsigned w1 = cvtpk_bf16(o[d0][rq * 4 + 2], o[d0][rq * 4 + 3]);
        int2 st2; st2.x = (int)w0; st2.y = (int)w1;
        *reinterpret_cast<int2*>(op + d0 * 32 + rq * 8 + hi * 4) = st2;
      }
    if (hi == 0) {
      int mlbase = (((head * 8 + c8) * 2 + part) * 2) * 128 + row;
      pml[mlbase] = mrow;
      pml[mlbase + 128] = lrow;
    }
  }
}

// Combine two KV-half partials for chunks 8..15 and write aows (perm'd bf16).
__global__ __launch_bounds__(256) void k_combine(const unsigned short* __restrict__ pO,
                                                 const float* __restrict__ pml,
                                                 unsigned short* __restrict__ aows) {
  int tid = blockIdx.x * 256 + threadIdx.x;
  int rg = tid >> 4;
  int d8 = tid & 15;
  int head = rg >> 10;
  int rem = rg & 1023;
  int c8 = rem >> 7;
  int row = rem & 127;
  int base2 = (head * 8 + c8) * 2;

  float m1 = pml[((base2 + 0) * 2 + 0) * 128 + row];
  float l1 = pml[((base2 + 0) * 2 + 1) * 128 + row];
  float m2 = pml[((base2 + 1) * 2 + 0) * 128 + row];
  float l2 = pml[((base2 + 1) * 2 + 1) * 128 + row];
  float m = fmaxf(m1, m2);
  float w1 = exp2f(m1 - m), w2 = exp2f(m2 - m);
  float inv = 1.f / (w1 * l1 + w2 * l2);

  const unsigned short* o1 = pO + (((size_t)(base2 + 0) * 128 + row) * 128) + d8 * 8;
  const unsigned short* o2 = pO + (((size_t)(base2 + 1) * 128 + row) * 128) + d8 * 8;
  union { int4 q; unsigned short us[8]; } ua, ub;
  ua.q = *reinterpret_cast<const int4*>(o1);
  ub.q = *reinterpret_cast<const int4*>(o2);
  float out[8];
#pragma unroll
  for (int e = 0; e < 8; ++e)
    out[e] = (w1 * b2f(ua.us[e]) + w2 * b2f(ub.us[e])) * inv;

  int b = head >> 4, h = head & 15;
  int s = (c8 + 8) * 128 + row;
  unsigned short* dst = aows + ((size_t)(b * SS + s)) * 2048 + h * 128;
  int d = d8 * 8;
  int dbase = d & ~31;
#pragma unroll
  for (int jj = 0; jj < 2; ++jj) {
    int t = ((d >> 2) + jj) & 7;
    int pos = ((t & 3) << 3) + ((t >> 2) << 2);
    unsigned wa = cvtpk_bf16(out[jj * 4 + 0], out[jj * 4 + 1]);
    unsigned wb = cvtpk_bf16(out[jj * 4 + 2], out[jj * 4 + 3]);
    int2 st2; st2.x = (int)wa; st2.y = (int)wb;
    *reinterpret_cast<int2*>(dst + dbase + pos) = st2;
  }
}

extern "C" void kernel_launch(void* const* d_in, const int* in_sizes, int n_in,
                              void* d_out, int out_size, void* d_ws, size_t ws_size,
                              hipStream_t stream) {
  (void)in_sizes; (void)n_in; (void)out_size; (void)ws_size;
  const float* x  = (const float*)d_in[0];
  const float* fc = (const float*)d_in[1];
  const float* fs = (const float*)d_in[2];
  const float* wq = (const float*)d_in[3];
  const float* wk = (const float*)d_in[4];
  const float* wv = (const float*)d_in[5];
  const float* wo = (const float*)d_in[6];
  float* out = (float*)d_out;
  float* koutF = out + (size_t)BB * SS * HIDD;                  // (B,KV,S,D)
  float* voutF = koutF + (size_t)BB * KVH * SS * DD;            // (B,KV,S,D)

  unsigned short* wcatT = (unsigned short*)d_ws;                // (3072, 2048)
  unsigned short* woT   = wcatT + (size_t)3072 * 2048;          // (2048, 2048)
  unsigned short* xbf   = woT + (size_t)2048 * 2048;            // (4096, 2048)
  unsigned short* qws   = xbf + (size_t)4096 * 2048;            // (B,H,S,D)
  unsigned short* kws   = qws + (size_t)BB * HH * SS * DD;      // d-interleaved
  unsigned short* vTws  = kws + (size_t)BB * KVH * SS * DD;     // s-interleaved
  unsigned short* aows  = vTws + (size_t)BB * KVH * DD * SS;    // (B*S, H*D)

  unsigned short* pO = xbf;
  float* pml = (float*)wcatT;

  hipFuncSetAttribute((const void*)k_gemm8<1, 256>,
                      hipFuncAttributeMaxDynamicSharedMemorySize, 131072);
  hipFuncSetAttribute((const void*)k_gemm8<0, 128>,
                      hipFuncAttributeMaxDynamicSharedMemorySize, 98304);

  k_convert<<<2048, 256, 0, stream>>>(x, xbf, (int)((size_t)4096 * 2048 / 4));
  dim3 tb(32, 8);
  k_transpose<<<dim3(64, 64), tb, 0, stream>>>(wq, wcatT, 2048, 2048);
  k_transpose<<<dim3(16, 64), tb, 0, stream>>>(wk, wcatT + (size_t)2048 * 2048, 2048, 512);
  k_transpose<<<dim3(16, 64), tb, 0, stream>>>(wv, wcatT + (size_t)2560 * 2048, 2048, 512);
  k_transpose<<<dim3(64, 64), tb, 0, stream>>>(wo, woT, 2048, 2048);

  k_gemm8<1, 256><<<dim3(16, 12), 512, 131072, stream>>>(xbf, wcatT, nullptr, qws, kws,
                                                         vTws, koutF, voutF, fc, fs);
  k_attn<<<768, 256, 0, stream>>>(qws, kws, vTws, aows, pO, pml);
  k_combine<<<2048, 256, 0, stream>>>(pO, pml, aows);
  k_gemm8<0, 128><<<dim3(32, 8), 512, 98304, stream>>>(aows, woT, out, nullptr, nullptr,
                                                       nullptr, nullptr, nullptr, nullptr, nullptr);
}

// Round 13
// 216.769 us; speedup vs baseline: 1.0901x; 1.0901x over previous
//
#include <hip/hip_runtime.h>
#include <stdint.h>

// Problem constants
#define BB 2
#define SS 2048
#define HIDD 2048
#define HH 16
#define KVH 4
#define DD 128
#define KDIM 2048

typedef short bf16x4 __attribute__((ext_vector_type(4)));
typedef short bf16x8 __attribute__((ext_vector_type(8)));
typedef float f32x4 __attribute__((ext_vector_type(4)));
typedef float f32x16 __attribute__((ext_vector_type(16)));

__device__ __forceinline__ unsigned short f2b(float f) {
  union { float f; unsigned u; } v; v.f = f;
  unsigned r = v.u + 0x7FFFu + ((v.u >> 16) & 1u);
  return (unsigned short)(r >> 16);
}

__device__ __forceinline__ float b2f(unsigned short u) {
  union { unsigned u; float f; } v; v.u = ((unsigned)u) << 16;
  return v.f;
}

__device__ __forceinline__ unsigned cvtpk_bf16(float a, float b) {
  unsigned r;
  asm("v_cvt_pk_bf16_f32 %0, %1, %2" : "=v"(r) : "v"(a), "v"(b));
  return r;
}

// async global->LDS, 16B per lane; LDS dest is wave-uniform base + lane*16
__device__ __forceinline__ void gload16(const unsigned short* g, unsigned short* l) {
  __builtin_amdgcn_global_load_lds(
      (const __attribute__((address_space(1))) unsigned int*)(g),
      (__attribute__((address_space(3))) unsigned int*)(l), 16, 0, 0);
}

// 16B LDS tile read
__device__ __forceinline__ bf16x8 ldT(const char* lds, int byteoff) {
  union { bf16x8 v; int4 q; } u;
  u.q = *reinterpret_cast<const int4*>(lds + byteoff);
  return u.v;
}

template <int N>
__device__ __forceinline__ void waitv() {
  if constexpr (N == 0) asm volatile("s_waitcnt vmcnt(0)" ::: "memory");
  else if constexpr (N == 1) asm volatile("s_waitcnt vmcnt(1)" ::: "memory");
  else if constexpr (N == 2) asm volatile("s_waitcnt vmcnt(2)" ::: "memory");
  else if constexpr (N == 3) asm volatile("s_waitcnt vmcnt(3)" ::: "memory");
  else if constexpr (N == 4) asm volatile("s_waitcnt vmcnt(4)" ::: "memory");
  else if constexpr (N == 5) asm volatile("s_waitcnt vmcnt(5)" ::: "memory");
  else asm volatile("s_waitcnt vmcnt(6)" ::: "memory");
}

// A/B-fragment interleave within a 16-elem group: element x stored at
// pos16(x) = (x&3) | ((x&4)<<1) | ((x&8)>>1); a contiguous 16B chunk
// holds x = base + {0,1,2,3,8,9,10,11} — the MFMA fragment order.
// K-dim interleave perm within 32-blocks: chunk g of block = fragment g.

__global__ __launch_bounds__(256) void k_convert(const float* __restrict__ in,
                                                 unsigned short* __restrict__ out, int n4) {
  int i = blockIdx.x * 256 + threadIdx.x;
  int stride = gridDim.x * 256;
  for (; i < n4; i += stride) {
    float4 v = reinterpret_cast<const float4*>(in)[i];
    ushort4 o;
    o.x = f2b(v.x); o.y = f2b(v.y); o.z = f2b(v.z); o.w = f2b(v.w);
    int ci = i & 511;
    int t = ci & 7;
    int ci2 = (ci & ~7) | ((t & 3) << 1) | (t >> 2);
    reinterpret_cast<ushort4*>(out)[(i & ~511) | ci2] = o;
  }
}

// in: (K,N) fp32 row-major -> out: (N,K) bf16 row-major with K-dim interleave perm
__global__ __launch_bounds__(256) void k_transpose(const float* __restrict__ in,
                                                   unsigned short* __restrict__ out,
                                                   int K, int N) {
  __shared__ float tile[32][33];
  int n0 = blockIdx.x * 32, k0 = blockIdx.y * 32;
  int tx = threadIdx.x, ty = threadIdx.y;
#pragma unroll
  for (int j = 0; j < 32; j += 8)
    tile[ty + j][tx] = in[(size_t)(k0 + ty + j) * N + n0 + tx];
  __syncthreads();
  int kp = ((tx >> 2) & 3) * 8 + (tx & 3) + ((tx >> 4) << 2);
#pragma unroll
  for (int j = 0; j < 32; j += 8)
    out[(size_t)(n0 + ty + j) * K + k0 + kp] = f2b(tile[tx][ty + j]);
}

// ===== gemm1: 128x192 tile, 512 blocks = 2/CU + 100% coverage =====
// 512 thr / 8 waves (2M x 4N), wave tile 64x48, BK=64, 80KB LDS (2-buf).
// One counted vmcnt(5) + two barriers per K-tile; prefetch distance ~2 iters;
// reads+MFMA compiler-scheduled; trailing lgkmcnt(0) = WAR guard.
// Fused epilogue: RoPE + q/k/v scatter (bf16 ws pre-interleaved for k_attn).
__global__ __launch_bounds__(512, 4) void k_gemm12(
    const unsigned short* __restrict__ A, const unsigned short* __restrict__ Bt,
    unsigned short* __restrict__ qws, unsigned short* __restrict__ kws,
    unsigned short* __restrict__ vTws, float* __restrict__ koutF,
    float* __restrict__ voutF, const float* __restrict__ cosT,
    const float* __restrict__ sinT) {
  __shared__ __align__(16) unsigned short lA[2][128 * 64];  // 32 KB
  __shared__ __align__(16) unsigned short lB[2][192 * 64];  // 48 KB
  const int bid = blockIdx.y * gridDim.x + blockIdx.x;      // 512 blocks
  const int swz = (bid & 7) * 64 + (bid >> 3);              // XCD-chunked, bijective
  const int rowbase = (swz & 31) * 128;
  const int colbase = (swz >> 5) * 192;
  const int tid = threadIdx.x;
  const int wv = tid >> 6, lane = tid & 63;
  const int wr = wv >> 2, wc = wv & 3;
  const int g = lane >> 4, c = lane & 15;

  // staging: A = 1024 16B-chunks (2/thread), B = 1536 (3/thread);
  // source chunk XOR-swizzled, LDS dest linear (rule 21).
  const unsigned short* aSrc[2];
  const unsigned short* bSrc[3];
  int aDst[2], bDst[3];
#pragma unroll
  for (int j = 0; j < 2; ++j) {
    int idx = j * 512 + tid;
    int row = idx >> 3, sl = idx & 7;
    int gch = sl ^ (row & 7);
    aSrc[j] = A + (size_t)(rowbase + row) * KDIM + gch * 8;
    aDst[j] = idx * 8;
  }
#pragma unroll
  for (int j = 0; j < 3; ++j) {
    int idx = j * 512 + tid;
    int row = idx >> 3, sl = idx & 7;
    int gch = sl ^ (row & 7);
    bSrc[j] = Bt + (size_t)(colbase + row) * KDIM + gch * 8;
    bDst[j] = idx * 8;
  }

  f32x4 acc[4][3] = {};
  const int NT = KDIM / 64;  // 32

  auto STAGE = [&](int buf, int kt) {
#pragma unroll
    for (int j = 0; j < 2; ++j)
      gload16(aSrc[j] + kt * 64, &lA[buf][0] + aDst[j]);
#pragma unroll
    for (int j = 0; j < 3; ++j)
      gload16(bSrc[j] + kt * 64, &lB[buf][0] + bDst[j]);
  };

  STAGE(0, 0);
  STAGE(1, 1);

  for (int t = 0; t < NT; ++t) {
    if (t + 1 < NT) { waitv<5>(); } else { waitv<0>(); }
    __builtin_amdgcn_sched_barrier(0);
    __builtin_amdgcn_s_barrier();

    const unsigned short* la = lA[t & 1];
    const unsigned short* lb = lB[t & 1];
    bf16x8 bfr[3][2];
#pragma unroll
    for (int nn = 0; nn < 3; ++nn) {
      int sr = wc * 48 + nn * 16 + c;
#pragma unroll
      for (int kk = 0; kk < 2; ++kk) {
        int slot = (kk * 4 + g) ^ (sr & 7);
        bfr[nn][kk] = *reinterpret_cast<const bf16x8*>(lb + sr * 64 + slot * 8);
      }
    }
#pragma unroll
    for (int mm = 0; mm < 4; ++mm) {
      int sr = wr * 64 + mm * 16 + c;
      int slot0 = g ^ (sr & 7);
      int slot1 = (4 + g) ^ (sr & 7);
      bf16x8 af0 = *reinterpret_cast<const bf16x8*>(la + sr * 64 + slot0 * 8);
      bf16x8 af1 = *reinterpret_cast<const bf16x8*>(la + sr * 64 + slot1 * 8);
#pragma unroll
      for (int nn = 0; nn < 3; ++nn) {
        acc[mm][nn] = __builtin_amdgcn_mfma_f32_16x16x32_bf16(af0, bfr[nn][0], acc[mm][nn], 0, 0, 0);
        acc[mm][nn] = __builtin_amdgcn_mfma_f32_16x16x32_bf16(af1, bfr[nn][1], acc[mm][nn], 0, 0, 0);
      }
    }
    asm volatile("s_waitcnt lgkmcnt(0)" ::: "memory");  // WAR guard before overwrite
    __builtin_amdgcn_s_barrier();
    if (t + 2 < NT) STAGE(t & 1, t + 2);
  }

  // epilogue: RoPE + scatter
#pragma unroll
  for (int m = 0; m < 4; ++m) {
#pragma unroll
    for (int n = 0; n < 3; ++n) {
#pragma unroll
      for (int i = 0; i < 4; ++i) {
        float val = acc[m][n][i];
        float partner = __shfl_xor(val, 1, 64);
        int R = rowbase + wr * 64 + m * 16 + g * 4 + i;
        int Cc = colbase + wc * 48 + n * 16 + c;
        int b = R >> 11, s = R & 2047;
        int d = Cc & 127;
        int j = d >> 1;
        float cs = cosT[s * 64 + j], sn = sinT[s * 64 + j];
        float ro = ((d & 1) == 0) ? (val * cs - partner * sn)
                                  : (partner * sn + val * cs);
        if (Cc < 2048) {
          int h = Cc >> 7;
          qws[((size_t)(b * HH + h) * SS + s) * DD + d] = f2b(ro);
        } else if (Cc < 2560) {
          int kvh = (Cc - 2048) >> 7;
          size_t idx = ((size_t)(b * KVH + kvh) * SS + s) * DD + d;
          koutF[idx] = ro;
          int d16 = d & 15;
          int dp = (d & ~15) | (d16 & 3) | ((d16 & 4) << 1) | ((d16 & 8) >> 1);
          kws[((size_t)(b * KVH + kvh) * SS + s) * DD + dp] = f2b(ro);
        } else {
          int kvh = (Cc - 2560) >> 7;
          size_t idx = ((size_t)(b * KVH + kvh) * SS + s) * DD + d;
          voutF[idx] = val;
          int s16 = s & 15;
          int sp = (s & ~15) | (s16 & 3) | ((s16 & 4) << 1) | ((s16 & 8) >> 1);
          vTws[((size_t)(b * KVH + kvh) * DD + d) * SS + sp] = f2b(val);
        }
      }
    }
  }
}

// ===== gemm2: BM x 256, 8-phase (R12 structure, BM=128 -> 256 blocks) =====
template <int EPI, int BM>
__global__ __launch_bounds__(512) void k_gemm8(
    const unsigned short* __restrict__ A, const unsigned short* __restrict__ Bt,
    float* __restrict__ outF,
    const float* __restrict__ cosT, const float* __restrict__ sinT) {
  constexpr int LA = BM / 128;
  constexpr int LB = 2;
  constexpr int ASTR = BM * 64;
  constexpr int BSTR = 256 * 64;
  constexpr int MF = BM / 64;
  constexpr int LSH = (BM == 256) ? 6 : 5;
  extern __shared__ __align__(16) unsigned short smem[];
  unsigned short* lAb = smem;
  unsigned short* lBb = smem + 2 * ASTR;

  const int bid = blockIdx.y * gridDim.x + blockIdx.x;
  const int nwg = gridDim.x * gridDim.y;
  const int mt = gridDim.x;
  const int swz = (bid & 7) * (nwg >> 3) + (bid >> 3);
  const int rowbase = (swz % mt) * BM;
  const int colbase = (swz / mt) * 256;

  const int tid = threadIdx.x;
  const int wv = tid >> 6, lane = tid & 63;
  const int wr = wv >> 2, wc = wv & 3;
  const int g = lane >> 4, c = lane & 15;

  const int srow8 = lane >> 3;
  const int gch = (lane & 7) ^ srow8;
  const unsigned short* aS[LA][2];
  const unsigned short* bS[2][2];
  int aOff[LA][2], bOff[2][2];
#pragma unroll
  for (int j = 0; j < LA; ++j)
#pragma unroll
    for (int h = 0; h < 2; ++h) {
      int s = wv * LA + j;
      int q = s * 8 + srow8;
      int rA = (q >> LSH) * (BM / 2) + h * (BM / 4) + (q & (BM / 4 - 1));
      aS[j][h] = A + (size_t)(rowbase + rA) * KDIM + gch * 8;
      aOff[j][h] = (h * (BM / 2) + s * 8) * 64;
    }
#pragma unroll
  for (int j = 0; j < 2; ++j)
#pragma unroll
    for (int h = 0; h < 2; ++h) {
      int s = wv * 2 + j;
      int q = s * 8 + srow8;
      int rB = (q >> 5) * 64 + h * 32 + (q & 31);
      bS[j][h] = Bt + (size_t)(colbase + rB) * KDIM + gch * 8;
      bOff[j][h] = (h * 128 + s * 8) * 64;
    }

  f32x4 acc[2 * MF][4] = {};
  bf16x8 af[MF][2], bfr[4][2];
  const int NT = KDIM / 64;

#define STAGE_A(buf, kt, h)                                               \
  _Pragma("unroll") for (int j = 0; j < LA; ++j)                          \
      gload16(aS[j][h] + (kt) * 64, lAb + (buf) * ASTR + aOff[j][h]);
#define STAGE_B(buf, kt, h)                                               \
  _Pragma("unroll") for (int j = 0; j < 2; ++j)                           \
      gload16(bS[j][h] + (kt) * 64, lBb + (buf) * BSTR + bOff[j][h]);
#define LDA(buf, mh)                                                      \
  _Pragma("unroll") for (int mm = 0; mm < MF; ++mm) {                     \
    int sr = (mh) * (BM / 2) + wr * (BM / 4) + mm * 16 + c;               \
    _Pragma("unroll") for (int kk = 0; kk < 2; ++kk) {                    \
      int slot = (kk * 4 + g) ^ (c & 7);                                  \
      af[mm][kk] = *reinterpret_cast<const bf16x8*>(                      \
          lAb + (buf) * ASTR + sr * 64 + slot * 8);                       \
    } }
#define LDB(buf, nh)                                                      \
  _Pragma("unroll") for (int nn = 0; nn < 2; ++nn) {                      \
    int sr = (nh) * 128 + wc * 32 + nn * 16 + c;                          \
    _Pragma("unroll") for (int kk = 0; kk < 2; ++kk) {                    \
      int slot = (kk * 4 + g) ^ (c & 7);                                  \
      bfr[(nh) * 2 + nn][kk] = *reinterpret_cast<const bf16x8*>(          \
          lBb + (buf) * BSTR + sr * 64 + slot * 8);                       \
    } }
#define MM(mh, nh)                                                        \
  _Pragma("unroll") for (int mm = 0; mm < MF; ++mm)                       \
  _Pragma("unroll") for (int nn = 0; nn < 2; ++nn)                        \
  _Pragma("unroll") for (int kk = 0; kk < 2; ++kk)                        \
    acc[(mh) * MF + mm][(nh) * 2 + nn] =                                  \
        __builtin_amdgcn_mfma_f32_16x16x32_bf16(                          \
            af[mm][kk], bfr[(nh) * 2 + nn][kk],                           \
            acc[(mh) * MF + mm][(nh) * 2 + nn], 0, 0, 0);
#define SCHB __builtin_amdgcn_sched_barrier(0);
#define SB __builtin_amdgcn_s_barrier();
#define LGKM asm volatile("s_waitcnt lgkmcnt(0)" ::: "memory");
#define MFMAWIN(mh, nh)                                                   \
  LGKM SCHB __builtin_amdgcn_s_setprio(1);                                \
  MM(mh, nh) __builtin_amdgcn_s_setprio(0); SCHB SB

  STAGE_A(0, 0, 0) STAGE_B(0, 0, 0) STAGE_B(0, 0, 1) STAGE_A(0, 0, 1)
  waitv<LA + LB>(); SCHB SB

  for (int kt = 0; kt < NT - 1; ++kt) {
    const int buf = kt & 1, nbuf = buf ^ 1;
    LDA(buf, 0) LDB(buf, 0)
    STAGE_A(nbuf, kt + 1, 0)
    waitv<2 * LA>(); SCHB SB
    MFMAWIN(0, 0)
    LDB(buf, 1)
    STAGE_B(nbuf, kt + 1, 0)
    waitv<LA + LB>(); SCHB SB
    MFMAWIN(0, 1)
    LDA(buf, 1)
    STAGE_B(nbuf, kt + 1, 1)
    SCHB SB
    MFMAWIN(1, 0)
    STAGE_A(nbuf, kt + 1, 1)
    waitv<LA + LB>(); SCHB SB
    MFMAWIN(1, 1)
  }
  {
    const int buf = (NT - 1) & 1;
    LDA(buf, 0) LDB(buf, 0)
    waitv<LA>(); SCHB SB
    MFMAWIN(0, 0)
    LDB(buf, 1)
    waitv<0>(); SCHB SB
    MFMAWIN(0, 1)
    LDA(buf, 1)
    SCHB SB
    MFMAWIN(1, 0)
    __builtin_amdgcn_s_setprio(1);
    MM(1, 1)
    __builtin_amdgcn_s_setprio(0);
  }

#pragma unroll
  for (int m = 0; m < 2 * MF; ++m)
#pragma unroll
    for (int n = 0; n < 4; ++n)
#pragma unroll
      for (int i = 0; i < 4; ++i) {
        int R = rowbase + wr * (BM / 2) + m * 16 + g * 4 + i;
        int Cc = colbase + wc * 64 + n * 16 + c;
        outF[(size_t)R * 2048 + Cc] = acc[m][n][i];
      }
  (void)cosT; (void)sinT;
#undef STAGE_A
#undef STAGE_B
#undef LDA
#undef LDB
#undef MM
#undef SCHB
#undef SB
#undef LGKM
#undef MFMAWIN
}

// LPT job table: 24 jobs/head sorted by tile count desc.
__constant__ int JC[24] = {7,15,15,14,14,6,13,13,12,12,5,11,11,10,10,4,9,9,8,8,3,2,1,0};
__constant__ int JP[24] = {0,0,1, 0,1, 0,0,1, 0,1, 0,0,1, 0,1, 0,0,1, 0,1, 0,0,0,0};

// Flash attention, 32x32 MFMA, double-swapped operands (unchanged from R7-R12).
__global__ __launch_bounds__(256, 2) void k_attn(const unsigned short* __restrict__ qws,
                                                 const unsigned short* __restrict__ kws,
                                                 const unsigned short* __restrict__ vT,
                                                 unsigned short* __restrict__ aows,
                                                 unsigned short* __restrict__ pO,
                                                 float* __restrict__ pml) {
  __shared__ __align__(16) char lds[2][32768];  // per buf: K 16KB | V 16KB
  const int tid = threadIdx.x;
  const int lane = tid & 63;
  const int w = tid >> 6;
  const int lq = lane & 31;
  const int hi = lane >> 5;

  const int bid = blockIdx.x;
  const int j = bid >> 5;
  const int y = bid & 31;
  const int head = 4 * (y & 7) + ((y >> 3) & 3);
  const int c = JC[j];
  const int part = JP[j];
  const bool split = (c >= 8);
  const int tstart = split ? (part ? (c + 1) : 0) : 0;
  const int tend = split ? (part ? (2 * c + 2) : (c + 1)) : (2 * c + 2);

  const int b = head >> 4, h = head & 15;
  const int kv = h >> 2;
  const int q0w = c * 128 + w * 32;
  const int qg = q0w + lq;
  const float cl2 = 0.12751743f;

  const unsigned short* qp = qws + ((size_t)(b * HH + h) * SS + qg) * DD;
  bf16x8 qf[8];
#pragma unroll
  for (int ks = 0; ks < 8; ++ks) {
    union { bf16x8 v8; bf16x4 v4[2]; } u;
    const unsigned short* p = qp + ks * 16 + hi * 4;
    u.v4[0] = *reinterpret_cast<const bf16x4*>(p);
    u.v4[1] = *reinterpret_cast<const bf16x4*>(p + 8);
    qf[ks] = u.v8;
  }

  const unsigned short* kbase = kws + (size_t)(b * KVH + kv) * SS * DD;
  const unsigned short* vbase = vT + (size_t)(b * KVH + kv) * DD * SS;

  const unsigned short* kSrc[4];
  const unsigned short* vSrc[4];
  int ldsOff[4];
#pragma unroll
  for (int j2 = 0; j2 < 4; ++j2) {
    int i = w + 4 * j2;
    int ks = i >> 1, half = i & 1;
    kSrc[j2] = kbase + (size_t)(half * 32 + (lane >> 1)) * DD + ks * 16 + (lane & 1) * 8;
    int kkv = i >> 2, d0v = i & 3;
    vSrc[j2] = vbase + (size_t)(d0v * 32 + (lane >> 1)) * SS + kkv * 16 + (lane & 1) * 8;
    ldsOff[j2] = i * 1024;
  }

  auto STAGE = [&](int t, int buf) {
    char* lK = lds[buf];
    char* lV = lds[buf] + 16384;
#pragma unroll
    for (int j2 = 0; j2 < 4; ++j2) {
      gload16(kSrc[j2] + (size_t)t * 64 * DD, (unsigned short*)(lK + ldsOff[j2]));
      gload16(vSrc[j2] + (size_t)t * 64, (unsigned short*)(lV + ldsOff[j2]));
    }
  };

  f32x16 o[4] = {};
  float mrow = -1e30f, lrow = 0.f;

  STAGE(tstart, 0);
  STAGE(tstart + 1, 1);
  asm volatile("s_waitcnt vmcnt(8)" ::: "memory");
  __builtin_amdgcn_sched_barrier(0);
  __builtin_amdgcn_s_barrier();

  for (int t = tstart; t < tend; ++t) {
    const int cur = (t - tstart) & 1;

    if (t * 64 <= q0w + 31) {
      const char* lK = lds[cur];
      const char* lV = lds[cur] + 16384;
      const bool full2 = (t * 64 + 32 <= q0w + 31);

      f32x16 s0 = {}, s1 = {};
      __builtin_amdgcn_s_setprio(1);
#pragma unroll
      for (int ks = 0; ks < 8; ++ks) {
        int off = ks * 2048 + lq * 32 + hi * 16;
        s0 = __builtin_amdgcn_mfma_f32_32x32x16_bf16(ldT(lK, off), qf[ks], s0, 0, 0, 0);
      }
      if (full2) {
#pragma unroll
        for (int ks = 0; ks < 8; ++ks) {
          int off = ks * 2048 + 1024 + lq * 32 + hi * 16;
          s1 = __builtin_amdgcn_mfma_f32_32x32x16_bf16(ldT(lK, off), qf[ks], s1, 0, 0, 0);
        }
      }
      __builtin_amdgcn_s_setprio(0);

      const int kq = t * 64 + 4 * hi - qg;
      float p[32];
      float rowmax = -1e30f;
      const bool m0 = (t * 64 + 31) > q0w;
#pragma unroll
      for (int r = 0; r < 16; ++r) {
        float v = s0[r] * cl2;
        if (m0) {
          int kl = (r & 3) + 8 * (r >> 2);
          if (kq + kl > 0) v = -1e30f;
        }
        p[r] = v;
        rowmax = fmaxf(rowmax, v);
      }
      if (full2) {
        const bool m1 = (t * 64 + 63) > q0w;
#pragma unroll
        for (int r = 0; r < 16; ++r) {
          float v = s1[r] * cl2;
          if (m1) {
            int kl = 32 + (r & 3) + 8 * (r >> 2);
            if (kq + kl > 0) v = -1e30f;
          }
          p[16 + r] = v;
          rowmax = fmaxf(rowmax, v);
        }
      }
      rowmax = fmaxf(rowmax, __shfl_xor(rowmax, 32, 64));

      if (__any(rowmax > mrow + 8.f)) {
        float mnew = fmaxf(mrow, rowmax);
        float fac = exp2f(mrow - mnew);
        mrow = mnew;
        lrow *= fac;
#pragma unroll
        for (int d0 = 0; d0 < 4; ++d0)
#pragma unroll
          for (int r = 0; r < 16; ++r) o[d0][r] *= fac;
      }

      float rsum = 0.f;
#pragma unroll
      for (int e = 0; e < 16; ++e) { p[e] = exp2f(p[e] - mrow); rsum += p[e]; }
      if (full2) {
#pragma unroll
        for (int e = 16; e < 32; ++e) { p[e] = exp2f(p[e] - mrow); rsum += p[e]; }
      }
      rsum += __shfl_xor(rsum, 32, 64);
      lrow += rsum;

      bf16x8 pf[4];
#pragma unroll
      for (int s4 = 0; s4 < 2; ++s4) {
        union { bf16x8 v; unsigned u[4]; } pu;
        int base = s4 * 8;
#pragma unroll
        for (int jj = 0; jj < 4; ++jj)
          pu.u[jj] = cvtpk_bf16(p[base + 2 * jj], p[base + 2 * jj + 1]);
        pf[s4] = pu.v;
      }
      if (full2) {
#pragma unroll
        for (int s4 = 2; s4 < 4; ++s4) {
          union { bf16x8 v; unsigned u[4]; } pu;
          int base = 16 + (s4 - 2) * 8;
#pragma unroll
          for (int jj = 0; jj < 4; ++jj)
            pu.u[jj] = cvtpk_bf16(p[base + 2 * jj], p[base + 2 * jj + 1]);
          pf[s4] = pu.v;
        }
      }

      __builtin_amdgcn_s_setprio(1);
#pragma unroll
      for (int d0 = 0; d0 < 4; ++d0)
#pragma unroll
        for (int kk = 0; kk < 2; ++kk) {
          int off = (kk * 4 + d0) * 1024 + lq * 32 + hi * 16;
          o[d0] = __builtin_amdgcn_mfma_f32_32x32x16_bf16(ldT(lV, off), pf[kk], o[d0], 0, 0, 0);
        }
      if (full2) {
#pragma unroll
        for (int d0 = 0; d0 < 4; ++d0)
#pragma unroll
          for (int kk = 2; kk < 4; ++kk) {
            int off = (kk * 4 + d0) * 1024 + lq * 32 + hi * 16;
            o[d0] = __builtin_amdgcn_mfma_f32_32x32x16_bf16(ldT(lV, off), pf[kk], o[d0], 0, 0, 0);
          }
      }
      __builtin_amdgcn_s_setprio(0);
    }

    if (t + 1 < tend) {
      __builtin_amdgcn_s_barrier();
      if (t + 2 < tend) {
        STAGE(t + 2, cur);
        asm volatile("s_waitcnt vmcnt(8)" ::: "memory");
      } else {
        asm volatile("s_waitcnt vmcnt(0)" ::: "memory");
      }
      __builtin_amdgcn_sched_barrier(0);
      __builtin_amdgcn_s_barrier();
    }
  }

  if (!split) {
    float linv = 1.f / lrow;
    unsigned short* op = aows + ((size_t)(b * SS + qg)) * 2048 + h * 128;
#pragma unroll
    for (int d0 = 0; d0 < 4; ++d0)
#pragma unroll
      for (int rq = 0; rq < 4; ++rq) {
        unsigned w0 = cvtpk_bf16(o[d0][rq * 4 + 0] * linv, o[d0][rq * 4 + 1] * linv);
        unsigned w1 = cvtpk_bf16(o[d0][rq * 4 + 2] * linv, o[d0][rq * 4 + 3] * linv);
        int2 st2; st2.x = (int)w0; st2.y = (int)w1;
        int pos = 8 * ((2 * rq + hi) & 3) + 4 * (rq >> 1);
        *reinterpret_cast<int2*>(op + d0 * 32 + pos) = st2;
      }
  } else {
    int c8 = c - 8;
    int row = qg - c * 128;
    unsigned short* op = pO + ((((size_t)(head * 8 + c8) * 2 + part) * 128) + row) * 128;
#pragma unroll
    for (int d0 = 0; d0 < 4; ++d0)
#pragma unroll
      for (int rq = 0; rq < 4; ++rq) {
        unsigned w0 = cvtpk_bf16(o[d0][rq * 4 + 0], o[d0][rq * 4 + 1]);
        unsigned w1 = cvtpk_bf16(o[d0][rq * 4 + 2], o[d0][rq * 4 + 3]);
        int2 st2; st2.x = (int)w0; st2.y = (int)w1;
        *reinterpret_cast<int2*>(op + d0 * 32 + rq * 8 + hi * 4) = st2;
      }
    if (hi == 0) {
      int mlbase = (((head * 8 + c8) * 2 + part) * 2) * 128 + row;
      pml[mlbase] = mrow;
      pml[mlbase + 128] = lrow;
    }
  }
}

// Combine two KV-half partials for chunks 8..15 and write aows (perm'd bf16).
__global__ __launch_bounds__(256) void k_combine(const unsigned short* __restrict__ pO,
                                                 const float* __restrict__ pml,
                                                 unsigned short* __restrict__ aows) {
  int tid = blockIdx.x * 256 + threadIdx.x;
  int rg = tid >> 4;
  int d8 = tid & 15;
  int head = rg >> 10;
  int rem = rg & 1023;
  int c8 = rem >> 7;
  int row = rem & 127;
  int base2 = (head * 8 + c8) * 2;

  float m1 = pml[((base2 + 0) * 2 + 0) * 128 + row];
  float l1 = pml[((base2 + 0) * 2 + 1) * 128 + row];
  float m2 = pml[((base2 + 1) * 2 + 0) * 128 + row];
  float l2 = pml[((base2 + 1) * 2 + 1) * 128 + row];
  float m = fmaxf(m1, m2);
  float w1 = exp2f(m1 - m), w2 = exp2f(m2 - m);
  float inv = 1.f / (w1 * l1 + w2 * l2);

  const unsigned short* o1 = pO + (((size_t)(base2 + 0) * 128 + row) * 128) + d8 * 8;
  const unsigned short* o2 = pO + (((size_t)(base2 + 1) * 128 + row) * 128) + d8 * 8;
  union { int4 q; unsigned short us[8]; } ua, ub;
  ua.q = *reinterpret_cast<const int4*>(o1);
  ub.q = *reinterpret_cast<const int4*>(o2);
  float out[8];
#pragma unroll
  for (int e = 0; e < 8; ++e)
    out[e] = (w1 * b2f(ua.us[e]) + w2 * b2f(ub.us[e])) * inv;

  int b = head >> 4, h = head & 15;
  int s = (c8 + 8) * 128 + row;
  unsigned short* dst = aows + ((size_t)(b * SS + s)) * 2048 + h * 128;
  int d = d8 * 8;
  int dbase = d & ~31;
#pragma unroll
  for (int jj = 0; jj < 2; ++jj) {
    int t = ((d >> 2) + jj) & 7;
    int pos = ((t & 3) << 3) + ((t >> 2) << 2);
    unsigned wa = cvtpk_bf16(out[jj * 4 + 0], out[jj * 4 + 1]);
    unsigned wb = cvtpk_bf16(out[jj * 4 + 2], out[jj * 4 + 3]);
    int2 st2; st2.x = (int)wa; st2.y = (int)wb;
    *reinterpret_cast<int2*>(dst + dbase + pos) = st2;
  }
}

extern "C" void kernel_launch(void* const* d_in, const int* in_sizes, int n_in,
                              void* d_out, int out_size, void* d_ws, size_t ws_size,
                              hipStream_t stream) {
  (void)in_sizes; (void)n_in; (void)out_size; (void)ws_size;
  const float* x  = (const float*)d_in[0];
  const float* fc = (const float*)d_in[1];
  const float* fs = (const float*)d_in[2];
  const float* wq = (const float*)d_in[3];
  const float* wk = (const float*)d_in[4];
  const float* wv = (const float*)d_in[5];
  const float* wo = (const float*)d_in[6];
  float* out = (float*)d_out;
  float* koutF = out + (size_t)BB * SS * HIDD;                  // (B,KV,S,D)
  float* voutF = koutF + (size_t)BB * KVH * SS * DD;            // (B,KV,S,D)

  unsigned short* wcatT = (unsigned short*)d_ws;                // (3072, 2048)
  unsigned short* woT   = wcatT + (size_t)3072 * 2048;          // (2048, 2048)
  unsigned short* xbf   = woT + (size_t)2048 * 2048;            // (4096, 2048)
  unsigned short* qws   = xbf + (size_t)4096 * 2048;            // (B,H,S,D)
  unsigned short* kws   = qws + (size_t)BB * HH * SS * DD;      // d-interleaved
  unsigned short* vTws  = kws + (size_t)BB * KVH * SS * DD;     // s-interleaved
  unsigned short* aows  = vTws + (size_t)BB * KVH * DD * SS;    // (B*S, H*D)

  unsigned short* pO = xbf;
  float* pml = (float*)wcatT;

  hipFuncSetAttribute((const void*)k_gemm8<0, 128>,
                      hipFuncAttributeMaxDynamicSharedMemorySize, 98304);

  k_convert<<<2048, 256, 0, stream>>>(x, xbf, (int)((size_t)4096 * 2048 / 4));
  dim3 tb(32, 8);
  k_transpose<<<dim3(64, 64), tb, 0, stream>>>(wq, wcatT, 2048, 2048);
  k_transpose<<<dim3(16, 64), tb, 0, stream>>>(wk, wcatT + (size_t)2048 * 2048, 2048, 512);
  k_transpose<<<dim3(16, 64), tb, 0, stream>>>(wv, wcatT + (size_t)2560 * 2048, 2048, 512);
  k_transpose<<<dim3(64, 64), tb, 0, stream>>>(wo, woT, 2048, 2048);

  k_gemm12<<<dim3(32, 16), 512, 0, stream>>>(xbf, wcatT, qws, kws, vTws,
                                             koutF, voutF, fc, fs);
  k_attn<<<768, 256, 0, stream>>>(qws, kws, vTws, aows, pO, pml);
  k_combine<<<2048, 256, 0, stream>>>(pO, pml, aows);
  k_gemm8<0, 128><<<dim3(32, 8), 512, 98304, stream>>>(aows, woT, out, nullptr, nullptr);
}